// Round 3
// baseline (766.051 us; speedup 1.0000x reference)
//
#include <hip/hip_runtime.h>
#include <cstdint>

#define DEVI __device__ __forceinline__

typedef int v4i __attribute__((ext_vector_type(4)));
typedef short v8s __attribute__((ext_vector_type(8)));
typedef float v4f __attribute__((ext_vector_type(4)));

// ---------- bf16 helpers (manual, RNE) ----------
DEVI float bf_lo(unsigned u) { return __uint_as_float(u << 16); }
DEVI float bf_hi(unsigned u) { return __uint_as_float(u & 0xffff0000u); }
DEVI float bf2f(unsigned short h) { return __uint_as_float(((unsigned)h) << 16); }
DEVI unsigned short f2bf(float f) {
  unsigned u = __float_as_uint(f);
  u += 0x7fffu + ((u >> 16) & 1u);
  return (unsigned short)(u >> 16);
}

// ---------- async global->LDS, 16B per lane (lane i lands at base + i*16) ----------
DEVI void async_copy16(void* l, const void* g) {
  __builtin_amdgcn_global_load_lds((const __attribute__((address_space(1))) void*)g,
                                   (__attribute__((address_space(3))) void*)l,
                                   16, 0, 0);
}

// ---------- wave (64-lane) reductions ----------
DEVI float wave_sum(float v) {
#pragma unroll
  for (int o = 32; o > 0; o >>= 1) v += __shfl_xor(v, o, 64);
  return v;
}
DEVI float wave_max(float v) {
#pragma unroll
  for (int o = 32; o > 0; o >>= 1) v = fmaxf(v, __shfl_xor(v, o, 64));
  return v;
}

// ---------- per-tensor sum(|w|) ----------
__global__ __launch_bounds__(256) void absum_kernel(const float* __restrict__ w, long n,
                                                    float* __restrict__ acc) {
  long stride = (long)gridDim.x * 1024;
  float s = 0.f;
  for (long i = ((long)blockIdx.x * 256 + threadIdx.x) * 4; i < n; i += stride) {
    float4 v = *(const float4*)(w + i);
    s += fabsf(v.x) + fabsf(v.y) + fabsf(v.z) + fabsf(v.w);
  }
  s = wave_sum(s);
  __shared__ float sc[4];
  int tid = threadIdx.x;
  if ((tid & 63) == 0) sc[tid >> 6] = s;
  __syncthreads();
  if (tid == 0) atomicAdd(acc, sc[0] + sc[1] + sc[2] + sc[3]);
}

// ---------- ternary weight quant into MFMA-fragment-major packed layout ----------
__global__ __launch_bounds__(256) void wquant_kernel(const float* __restrict__ w, long n4,
                                                     const float* __restrict__ acc, float cnt,
                                                     signed char* __restrict__ out, int kshift) {
  float wsv = fmaxf(acc[0] / cnt, 1e-5f);
  float inv = 1.0f / wsv;
  int K = 1 << kshift;
  long stride = (long)gridDim.x * 256;
  for (long i = (long)blockIdx.x * 256 + threadIdx.x; i < n4; i += stride) {
    float4 v = *(const float4*)(w + i * 4);
    int q0 = max(-1, min(1, (int)rintf(v.x * inv)));
    int q1 = max(-1, min(1, (int)rintf(v.y * inv)));
    int q2 = max(-1, min(1, (int)rintf(v.z * inv)));
    int q3 = max(-1, min(1, (int)rintf(v.w * inv)));
    unsigned r = (q0 & 0xff) | ((q1 & 0xff) << 8) | ((q2 & 0xff) << 16) | ((q3 & 0xff) << 24);
    long flat = i * 4;
    int n = (int)(flat >> kshift);
    int k = (int)(flat & (K - 1));
    long off = ((long)(n >> 4) * (K >> 6) + (k >> 6)) * 1024 +
               (((k >> 4) & 3) * 16 + (n & 15)) * 16 + (k & 15);
    *(unsigned*)(out + off) = r;
  }
}

// ---------- fused LayerNorm + per-token absmax int8 quant (C=2048, 1 block/row) ----------
__global__ __launch_bounds__(256) void ln_quant_kernel(const float* __restrict__ x,
                                                       const float* __restrict__ g,
                                                       const float* __restrict__ b,
                                                       signed char* __restrict__ q,
                                                       float* __restrict__ inv_s) {
  int row = blockIdx.x, tid = threadIdx.x;
  const float4* xr = (const float4*)(x + (long)row * 2048);
  float4 a0 = xr[tid * 2], a1 = xr[tid * 2 + 1];
  float xv[8] = {a0.x, a0.y, a0.z, a0.w, a1.x, a1.y, a1.z, a1.w};
  float s = 0.f, s2 = 0.f;
#pragma unroll
  for (int e = 0; e < 8; ++e) { s += xv[e]; s2 += xv[e] * xv[e]; }
  s = wave_sum(s); s2 = wave_sum(s2);
  __shared__ float sc[8];
  if ((tid & 63) == 0) { sc[tid >> 6] = s; sc[4 + (tid >> 6)] = s2; }
  __syncthreads();
  float mean = (sc[0] + sc[1] + sc[2] + sc[3]) * (1.f / 2048.f);
  float var = (sc[4] + sc[5] + sc[6] + sc[7]) * (1.f / 2048.f) - mean * mean;
  float rs = 1.0f / sqrtf(var + 1e-5f);
  float4 g0 = ((const float4*)g)[tid * 2], g1v = ((const float4*)g)[tid * 2 + 1];
  float4 b0 = ((const float4*)b)[tid * 2], b1v = ((const float4*)b)[tid * 2 + 1];
  float gv[8] = {g0.x, g0.y, g0.z, g0.w, g1v.x, g1v.y, g1v.z, g1v.w};
  float bv[8] = {b0.x, b0.y, b0.z, b0.w, b1v.x, b1v.y, b1v.z, b1v.w};
  float y[8];
  float am = 0.f;
#pragma unroll
  for (int e = 0; e < 8; ++e) {
    y[e] = (xv[e] - mean) * rs * gv[e] + bv[e];
    am = fmaxf(am, fabsf(y[e]));
  }
  am = wave_max(am);
  __syncthreads();
  if ((tid & 63) == 0) sc[tid >> 6] = am;
  __syncthreads();
  am = fmaxf(fmaxf(sc[0], sc[1]), fmaxf(sc[2], sc[3]));
  float c = fmaxf(am, 1e-5f);
  float xs = 127.0f / c;
  union { signed char c8[8]; int2 v; } u;
#pragma unroll
  for (int e = 0; e < 8; ++e) {
    int t = (int)rintf(y[e] * xs);
    u.c8[e] = (signed char)max(-128, min(127, t));
  }
  ((int2*)(q + (long)row * 2048))[tid] = u.v;
  if (tid == 0) inv_s[row] = c * (1.0f / 127.0f);
}

// ---------- per-row absmax int8 quant from bf16 rows (R = 2048 or 8192) ----------
template <int R>
__global__ __launch_bounds__(256) void row_quant_kernel(const unsigned short* __restrict__ in,
                                                        signed char* __restrict__ q,
                                                        float* __restrict__ inv_s) {
  constexpr int V = R / 2048;
  int row = blockIdx.x, tid = threadIdx.x;
  const uint4* p = (const uint4*)(in + (long)row * R);
  float y[V * 8];
  float am = 0.f;
#pragma unroll
  for (int v = 0; v < V; ++v) {
    uint4 d = p[tid * V + v];
    unsigned xw[4] = {d.x, d.y, d.z, d.w};
#pragma unroll
    for (int k = 0; k < 4; ++k) {
      y[v * 8 + k * 2] = bf_lo(xw[k]);
      y[v * 8 + k * 2 + 1] = bf_hi(xw[k]);
    }
  }
#pragma unroll
  for (int e = 0; e < V * 8; ++e) am = fmaxf(am, fabsf(y[e]));
  am = wave_max(am);
  __shared__ float sc[4];
  if ((tid & 63) == 0) sc[tid >> 6] = am;
  __syncthreads();
  am = fmaxf(fmaxf(sc[0], sc[1]), fmaxf(sc[2], sc[3]));
  float c = fmaxf(am, 1e-5f);
  float xs = 127.0f / c;
  signed char* qr = q + (long)row * R;
#pragma unroll
  for (int v = 0; v < V; ++v) {
    union { signed char c8[8]; long l; } u;
#pragma unroll
    for (int k = 0; k < 8; ++k) {
      int t = (int)rintf(y[v * 8 + k] * xs);
      u.c8[k] = (signed char)max(-128, min(127, t));
    }
    ((long*)qr)[tid * V + v] = u.l;
  }
  if (tid == 0) inv_s[row] = c * (1.0f / 127.0f);
}

// ---------- int8 MFMA GEMM (128x128 tile, 2-phase) — kept for N=2048 gemms ----------
template <int EPI>
__global__ __launch_bounds__(256)
void gemm_i8(const signed char* __restrict__ A, const signed char* __restrict__ Bp,
             int N, int K, const float* __restrict__ wacc, float wcount,
             const float* __restrict__ inv_s, const float* __restrict__ res,
             void* __restrict__ outp) {
  __shared__ signed char As[2][128 * 128];
  int tid = threadIdx.x;
  int idx = blockIdx.x;
  int r8 = idx & 7, rest = idx >> 3;
  int mb = rest & 31;
  int nb = (rest >> 5) * 8 + r8;
  int m0 = mb * 128, n0 = nb * 128;
  int w = tid >> 6, lane = tid & 63;
  int wm = (w >> 1) * 64, wn = (w & 1) * 64;
  int lr = lane & 15, q = lane >> 4;

  v4i acc[4][4] = {};

  int srow = w * 32 + (lane >> 3);
  int scol = (lane & 7) ^ ((lane >> 3) & 7);
  const signed char* ga = A + (long)(m0 + srow) * K + scol * 16;

  int nkb = K >> 7;
  const signed char* gbp[4];
#pragma unroll
  for (int t = 0; t < 4; ++t) {
    int ntile = (n0 >> 4) + (w & 1) * 4 + t;
    gbp[t] = Bp + (long)ntile * (K >> 6) * 1024 + lane * 16;
  }

  v4i bf_cur[2][4], bf_nxt[2][4];
#pragma unroll
  for (int i = 0; i < 4; ++i)
    async_copy16(&As[0][(w * 256 + i * 64) * 16], ga + i * 8 * K);
#pragma unroll
  for (int s = 0; s < 2; ++s)
#pragma unroll
    for (int t = 0; t < 4; ++t) bf_cur[s][t] = *(const v4i*)(gbp[t] + s * 1024);
  __syncthreads();

  int buf = 0;
  for (int kb = 0; kb < nkb; ++kb) {
    if (kb + 1 < nkb) {
#pragma unroll
      for (int i = 0; i < 4; ++i)
        async_copy16(&As[buf ^ 1][(w * 256 + i * 64) * 16], ga + i * 8 * K + (kb + 1) * 128);
#pragma unroll
      for (int s = 0; s < 2; ++s)
#pragma unroll
        for (int t = 0; t < 4; ++t)
          bf_nxt[s][t] = *(const v4i*)(gbp[t] + ((kb + 1) * 2 + s) * 1024);
    }
#pragma unroll
    for (int s = 0; s < 2; ++s) {
      v4i af[4];
#pragma unroll
      for (int i = 0; i < 4; ++i) {
        int row = wm + i * 16 + lr;
        af[i] = *(const v4i*)(&As[buf][(row * 8 + ((s * 4 + q) ^ (lr & 7))) * 16]);
      }
#pragma unroll
      for (int i = 0; i < 4; ++i)
#pragma unroll
        for (int j = 0; j < 4; ++j)
          acc[i][j] = __builtin_amdgcn_mfma_i32_16x16x64_i8(af[i], bf_cur[s][j], acc[i][j], 0, 0, 0);
    }
    __syncthreads();
    if (kb + 1 < nkb) {
#pragma unroll
      for (int s = 0; s < 2; ++s)
#pragma unroll
        for (int t = 0; t < 4; ++t) bf_cur[s][t] = bf_nxt[s][t];
    }
    buf ^= 1;
  }

  float wsv = fmaxf(wacc[0] / wcount, 1e-5f);
#pragma unroll
  for (int i = 0; i < 4; ++i) {
    int rowbase = m0 + wm + i * 16 + (lane >> 4) * 4;
#pragma unroll
    for (int r = 0; r < 4; ++r) {
      int row = rowbase + r;
      float s = wsv * inv_s[row];
#pragma unroll
      for (int j = 0; j < 4; ++j) {
        int col = n0 + wn + j * 16 + (lane & 15);
        long off = (long)row * N + col;
        float v = (float)acc[i][j][r] * s;
        if constexpr (EPI == 0) {
          ((unsigned short*)outp)[off] = f2bf(v);
        } else if constexpr (EPI == 1) {
          ((float*)outp)[off] = v + res[off];
        } else {
          float gvv = 0.5f * v * (1.0f + erff(v * 0.70710678118654752f));
          ((unsigned short*)outp)[off] = f2bf(gvv);
        }
      }
    }
  }
}

// ========== int8 MFMA GEMM "big": 256x256 tile, BK=128, 8 waves (2M x 4N), phase-split ==========
// All vm ops in the counted-vmcnt window are order-pinned: staging = global_load_lds intrinsics,
// B fragments = asm-volatile global_load_dwordx4 (the compiler can no longer sink/hoist them, which
// caused round-2's race). Per-iteration pinned issue order: [4 staging][4 B][4 B]. Waits (manual,
// compiler doesn't track asm B regs): phase0 vmcnt(4) = prev B drained / staging in flight;
// phase3 vmcnt(8) = staging drained / next B in flight. Last 2 iterations peeled (pipeline drain).
#define GIB_PHASE(RB, BFC, VMISSUE, WAITSTR, TAIL)                                      \
  {                                                                                     \
    v4i af[4];                                                                          \
    _Pragma("unroll") for (int j = 0; j < 4; ++j) {                                     \
      int m = 2 * p + (j >> 1), kc = j & 1;                                             \
      int row = wm + m * 16 + lr;                                                       \
      af[j] = *(const v4i*)(&As[(RB)][(row * 8 + ((kc * 4 + q) ^ (lr & 7))) * 16]);     \
    }                                                                                   \
    __builtin_amdgcn_sched_barrier(0);                                                  \
    VMISSUE                                                                             \
    __builtin_amdgcn_sched_barrier(0);                                                  \
    __builtin_amdgcn_s_barrier();                                                       \
    asm volatile(WAITSTR ::: "memory");                                                 \
    __builtin_amdgcn_sched_barrier(0);                                                  \
    __builtin_amdgcn_s_setprio(1);                                                      \
    _Pragma("unroll") for (int j = 0; j < 2; ++j)                                       \
      _Pragma("unroll") for (int t = 0; t < 4; ++t)                                     \
        _Pragma("unroll") for (int kc = 0; kc < 2; ++kc)                                \
          acc[2 * p + j][t] = __builtin_amdgcn_mfma_i32_16x16x64_i8(                    \
              af[j * 2 + kc], BFC[kc][t], acc[2 * p + j][t], 0, 0, 0);                  \
    __builtin_amdgcn_s_setprio(0);                                                      \
    __builtin_amdgcn_sched_barrier(0);                                                  \
    TAIL                                                                                \
    __builtin_amdgcn_s_barrier();                                                       \
  }

#define GIB_STAGE(RBD)                                                                  \
  _Pragma("unroll") for (int i = 0; i < 4; ++i)                                         \
    async_copy16(&As[(RBD)][(w * 256 + i * 64) * 16],                                   \
                 ga + (long)i * 8 * K + (kb + 1) * 128);

#define GIB_LOADB(DST, HALF)                                                            \
  _Pragma("unroll") for (int t = 0; t < 4; ++t)                                         \
    asm volatile("global_load_dwordx4 %0, %1, off"                                      \
                 : "=v"(DST[HALF][t])                                                   \
                 : "v"(gbp[t] + (long)((kb + 1) * 2 + (HALF)) * 1024)                   \
                 : "memory");

#define GIB_VMTAIL                                                                      \
  asm volatile("s_waitcnt vmcnt(8)" ::: "memory");                                      \
  __builtin_amdgcn_sched_barrier(0);

#define GIB_ITER_MAIN(RB, BFC, BFN)                                                     \
  {                                                                                     \
    { constexpr int p = 0;                                                              \
      GIB_PHASE(RB, BFC, GIB_STAGE((RB) ^ 1), "s_waitcnt vmcnt(4) lgkmcnt(0)", ) }      \
    { constexpr int p = 1;                                                              \
      GIB_PHASE(RB, BFC, GIB_LOADB(BFN, 0), "s_waitcnt lgkmcnt(0)", ) }                 \
    { constexpr int p = 2;                                                              \
      GIB_PHASE(RB, BFC, GIB_LOADB(BFN, 1), "s_waitcnt lgkmcnt(0)", ) }                 \
    { constexpr int p = 3;                                                              \
      GIB_PHASE(RB, BFC, , "s_waitcnt lgkmcnt(0)", GIB_VMTAIL) }                        \
  }

#define GIB_ITER_LAST(RB, BFC)                                                          \
  {                                                                                     \
    { constexpr int p = 0;                                                              \
      GIB_PHASE(RB, BFC, , "s_waitcnt vmcnt(0) lgkmcnt(0)", ) }                         \
    { constexpr int p = 1;                                                              \
      GIB_PHASE(RB, BFC, , "s_waitcnt lgkmcnt(0)", ) }                                  \
    { constexpr int p = 2;                                                              \
      GIB_PHASE(RB, BFC, , "s_waitcnt lgkmcnt(0)", ) }                                  \
    { constexpr int p = 3;                                                              \
      GIB_PHASE(RB, BFC, , "s_waitcnt lgkmcnt(0)", ) }                                  \
  }

template <int EPI>
__global__ __launch_bounds__(512, 2)
void gemm_i8_big(const signed char* __restrict__ A, const signed char* __restrict__ Bp,
                 int N, int K, const float* __restrict__ wacc, float wcount,
                 const float* __restrict__ inv_s, const float* __restrict__ res,
                 void* __restrict__ outp) {
  __shared__ signed char As[2][256 * 128];
  int tid = threadIdx.x;
  // decode: idx = (n&7) + 8*((n>>3)*16 + m)   [NB % 8 == 0, MB = 16]
  int idx = blockIdx.x;
  int r8 = idx & 7, rest = idx >> 3;
  int mb = rest & 15;
  int nb = (rest >> 4) * 8 + r8;
  int m0 = mb * 256, n0 = nb * 256;
  int w = tid >> 6, lane = tid & 63;
  int wm = (w >> 2) * 128, wn = (w & 3) * 64;
  int lr = lane & 15, q = lane >> 4;

  v4i acc[8][4] = {};

  // A staging: 256 rows x 8 chunks(16B); wave w covers rows [w*32, w*32+32), 4 instrs.
  // LDS chunk u = row*8 + (cg ^ (row&7)); lane-linear dest (w*256 + i*64 + lane)*16.
  int srow = w * 32 + (lane >> 3);
  int scol = (lane & 7) ^ ((lane >> 3) & 7);
  const signed char* ga = A + (long)(m0 + srow) * K + scol * 16;

  int nkt = K >> 7;  // 16 for K=2048 (even, >= 4; loop below relies on this)
  const signed char* gbp[4];
#pragma unroll
  for (int t = 0; t < 4; ++t) {
    int ntile = ((n0 + wn) >> 4) + t;
    gbp[t] = Bp + (long)ntile * (K >> 6) * 1024 + lane * 16;
  }

  v4i bfA[2][4], bfB[2][4];
  // prologue: stage A tile 0 (4 vm), then B frags tile 0 (8 vm, asm-pinned order).
#pragma unroll
  for (int i = 0; i < 4; ++i)
    async_copy16(&As[0][(w * 256 + i * 64) * 16], ga + (long)i * 8 * K);
  __builtin_amdgcn_sched_barrier(0);
#pragma unroll
  for (int s = 0; s < 2; ++s)
#pragma unroll
    for (int t = 0; t < 4; ++t)
      asm volatile("global_load_dwordx4 %0, %1, off"
                   : "=v"(bfA[s][t]) : "v"(gbp[t] + (long)s * 1024) : "memory");
  __builtin_amdgcn_sched_barrier(0);
  asm volatile("s_waitcnt vmcnt(8)" ::: "memory");  // tile-0 staging landed; B in flight
  __builtin_amdgcn_sched_barrier(0);
  __builtin_amdgcn_s_barrier();

  for (int kb2 = 0; kb2 < nkt - 2; kb2 += 2) {
    { int kb = kb2;     GIB_ITER_MAIN(0, bfA, bfB) }
    { int kb = kb2 + 1; GIB_ITER_MAIN(1, bfB, bfA) }
  }
  { int kb = nkt - 2; GIB_ITER_MAIN(0, bfA, bfB) }
  GIB_ITER_LAST(1, bfB)

  float wsv = fmaxf(wacc[0] / wcount, 1e-5f);
#pragma unroll
  for (int m = 0; m < 8; ++m) {
    int rowbase = m0 + wm + m * 16 + q * 4;
#pragma unroll
    for (int r = 0; r < 4; ++r) {
      int row = rowbase + r;
      float s = wsv * inv_s[row];
#pragma unroll
      for (int j = 0; j < 4; ++j) {
        int col = n0 + wn + j * 16 + lr;
        long off = (long)row * N + col;
        float v = (float)acc[m][j][r] * s;
        if constexpr (EPI == 0) {
          ((unsigned short*)outp)[off] = f2bf(v);
        } else if constexpr (EPI == 1) {
          ((float*)outp)[off] = v + res[off];
        } else {
          float gvv = 0.5f * v * (1.0f + erff(v * 0.70710678118654752f));
          ((unsigned short*)outp)[off] = f2bf(gvv);
        }
      }
    }
  }
}

// ================== MFMA flash attention v2 (verified round 1) ==================
DEVI int sigma_k(int y) {
  return (y & 35) | (((y >> 3) & 1) << 4) | (((y >> 2) & 1) << 3) | (((y >> 4) & 1) << 2);
}

DEVI void stage_k(const unsigned short* kbase_g, int k0, char* ks, int w, int lane) {
#pragma unroll
  for (int i = 0; i < 2; ++i) {
    int c = i * 512 + w * 64 + lane;
    int key = c >> 4;
    int dch = (c & 15) ^ (key & 15);
    async_copy16(ks + (i * 512 + w * 64) * 16,
                 kbase_g + (long)(k0 + sigma_k(key)) * 6144 + dch * 8);
  }
}

DEVI void load_v(const unsigned short* vbase_g, int k0, int kg, int dg, uint2* lv) {
#pragma unroll
  for (int i = 0; i < 4; ++i)
    lv[i] = *(const uint2*)(vbase_g + (long)(k0 + kg * 4 + i) * 6144 + dg * 4);
}

DEVI void repack_v(const uint2* lv, unsigned short* vt, int kg, int dg) {
#pragma unroll
  for (int jd = 0; jd < 4; ++jd) {
    union { unsigned short s[4]; unsigned long long u; } pk;
#pragma unroll
    for (int i = 0; i < 4; ++i) {
      unsigned word = (jd < 2) ? lv[i].x : lv[i].y;
      pk.s[i] = (unsigned short)((jd & 1) ? (word >> 16) : (word & 0xffffu));
    }
    *(unsigned long long*)(vt + (dg * 4 + jd) * 72 + kg * 4) = pk.u;
  }
}

__global__ __launch_bounds__(512, 4)
void fattn_kernel(const unsigned short* __restrict__ qkv, unsigned short* __restrict__ out) {
  constexpr int VROW = 72;
  __shared__ __align__(16) char Ks[2][16384];
  __shared__ __align__(16) unsigned short Vt[2][128 * VROW];

  int tid = threadIdx.x;
  int w = tid >> 6, lane = tid & 63;
  int l = lane & 15, q = lane >> 4;
  int idx = blockIdx.x;
  int r8 = idx & 7, rest = idx >> 3;
  int qt = rest & 15;
  int bh = (rest >> 4) * 8 + r8;
  int bb = bh >> 4, hh = bh & 15;
  const unsigned short* base = qkv + (long)bb * 2048 * 6144;
  int q0 = qt * 128;

  v8s aq[4];
  {
    const unsigned short* qrow = base + (long)(q0 + w * 16 + l) * 6144 + hh * 128;
#pragma unroll
    for (int kf = 0; kf < 4; ++kf) aq[kf] = *(const v8s*)(qrow + kf * 32 + q * 8);
  }

  v4f oacc[8] = {};
  float mrow = -1e30f, lrow = 0.f;

  const unsigned short* kbase_g = base + 2048 + hh * 128;
  const unsigned short* vbase_g = base + 4096 + hh * 128;
  int kg = tid & 15, dg = tid >> 4;
  constexpr float SC = 0.08838834764831845f;

  stage_k(kbase_g, 0, Ks[0], w, lane);
  uint2 lv[4];
  load_v(vbase_g, 0, kg, dg, lv);
  repack_v(lv, Vt[0], kg, dg);
  __syncthreads();

  for (int kt = 0; kt < 32; ++kt) {
    const char* ksc = Ks[kt & 1];
    const unsigned short* vtc = Vt[kt & 1];
    bool more = kt < 31;
    if (more) {
      stage_k(kbase_g, (kt + 1) * 64, Ks[(kt + 1) & 1], w, lane);
      load_v(vbase_g, (kt + 1) * 64, kg, dg, lv);
    }

    v4f sacc[4] = {};
#pragma unroll
    for (int kf = 0; kf < 4; ++kf) {
#pragma unroll
      for (int t = 0; t < 4; ++t) {
        int ch = (t * 16 + l) * 16 + ((kf * 4 + q) ^ l);
        v8s bk = *(const v8s*)(ksc + ch * 16);
        sacc[t] = __builtin_amdgcn_mfma_f32_16x16x32_bf16(bk, aq[kf], sacc[t], 0, 0, 0);
      }
    }

    float rm = -1e30f;
#pragma unroll
    for (int t = 0; t < 4; ++t)
#pragma unroll
      for (int r = 0; r < 4; ++r) rm = fmaxf(rm, sacc[t][r]);
    rm *= SC;
    rm = fmaxf(rm, __shfl_xor(rm, 16, 64));
    rm = fmaxf(rm, __shfl_xor(rm, 32, 64));
    float mnew = fmaxf(mrow, rm);
    if (__any(mnew - mrow > 8.0f)) {
      float alpha = __expf(mrow - mnew);
      mrow = mnew;
      lrow *= alpha;
#pragma unroll
      for (int r = 0; r < 4; ++r) {
        float ao = __shfl(alpha, q * 4 + r, 64);
#pragma unroll
        for (int t = 0; t < 8; ++t) oacc[t][r] *= ao;
      }
    }
    float rs = 0.f;
#pragma unroll
    for (int t = 0; t < 4; ++t)
#pragma unroll
      for (int r = 0; r < 4; ++r) {
        float pv = __expf(fmaf(sacc[t][r], SC, -mrow));
        sacc[t][r] = pv;
        rs += pv;
      }
    rs += __shfl_xor(rs, 16, 64);
    rs += __shfl_xor(rs, 32, 64);
    lrow += rs;

    union { unsigned u[4]; v8s s; } pa[2];
#pragma unroll
    for (int s2 = 0; s2 < 2; ++s2)
#pragma unroll
      for (int j2 = 0; j2 < 4; ++j2) {
        int tt = s2 * 2 + (j2 >> 1);
        int r0 = (j2 & 1) * 2;
        unsigned wrd;
        asm("v_cvt_pk_bf16_f32 %0, %1, %2"
            : "=v"(wrd) : "v"(sacc[tt][r0]), "v"(sacc[tt][r0 + 1]));
        pa[s2].u[j2] = wrd;
      }

#pragma unroll
    for (int s2 = 0; s2 < 2; ++s2) {
#pragma unroll
      for (int t = 0; t < 8; ++t) {
        v8s bv = *(const v8s*)(vtc + (t * 16 + l) * VROW + s2 * 32 + q * 8);
        oacc[t] = __builtin_amdgcn_mfma_f32_16x16x32_bf16(pa[s2].s, bv, oacc[t], 0, 0, 0);
      }
    }

    if (more) repack_v(lv, Vt[(kt + 1) & 1], kg, dg);
    __syncthreads();
  }

#pragma unroll
  for (int r = 0; r < 4; ++r) {
    float lr = __shfl(lrow, q * 4 + r, 64);
    float inv = 1.0f / lr;
    long grow = (long)bb * 2048 + q0 + w * 16 + q * 4 + r;
    unsigned short* orow = out + grow * 2048 + hh * 128;
#pragma unroll
    for (int t = 0; t < 8; ++t) orow[t * 16 + l] = f2bf(oacc[t][r] * inv);
  }
}

extern "C" void kernel_launch(void* const* d_in, const int* in_sizes, int n_in,
                              void* d_out, int out_size, void* d_ws, size_t ws_size,
                              hipStream_t stream) {
  (void)in_sizes; (void)n_in; (void)out_size; (void)ws_size;
  const float* x      = (const float*)d_in[0];
  const float* w_qkv  = (const float*)d_in[1];
  const float* w_proj = (const float*)d_in[2];
  const float* w_fc1  = (const float*)d_in[3];
  const float* w_fc2  = (const float*)d_in[4];
  const float* g1 = (const float*)d_in[5];
  const float* b1 = (const float*)d_in[6];
  const float* g2 = (const float*)d_in[7];
  const float* b2 = (const float*)d_in[8];

  char* wsb = (char*)d_ws;
  float* acc = (float*)wsb;
  size_t off = 256;
  signed char* q8 = (signed char*)(wsb + off);       off += (size_t)4096 * 8192;
  float* invs = (float*)(wsb + off);                 off += 16384;
  signed char* wq_qkv = (signed char*)(wsb + off);   off += (size_t)6144 * 2048;
  signed char* wq_proj = (signed char*)(wsb + off);  off += (size_t)2048 * 2048;
  signed char* wq_fc1 = (signed char*)(wsb + off);   off += (size_t)8192 * 2048;
  signed char* wq_fc2 = (signed char*)(wsb + off);   off += (size_t)2048 * 8192;
  unsigned short* qkvh = (unsigned short*)(wsb + off); off += (size_t)4096 * 8192 * 2;
  unsigned short* obuf = (unsigned short*)(wsb + off); off += (size_t)4096 * 2048 * 2;
  float* x2 = (float*)(wsb + off);                   off += (size_t)4096 * 2048 * 4;

  hipMemsetAsync(acc, 0, 256, stream);

  absum_kernel<<<dim3(1024), 256, 0, stream>>>(w_qkv, (long)6144 * 2048, acc + 0);
  absum_kernel<<<dim3(512),  256, 0, stream>>>(w_proj, (long)2048 * 2048, acc + 1);
  absum_kernel<<<dim3(1024), 256, 0, stream>>>(w_fc1, (long)8192 * 2048, acc + 2);
  absum_kernel<<<dim3(1024), 256, 0, stream>>>(w_fc2, (long)2048 * 8192, acc + 3);

  wquant_kernel<<<dim3(1024), 256, 0, stream>>>(w_qkv, (long)6144 * 2048 / 4, acc + 0, 12582912.f, wq_qkv, 11);
  wquant_kernel<<<dim3(1024), 256, 0, stream>>>(w_proj, (long)2048 * 2048 / 4, acc + 1, 4194304.f, wq_proj, 11);
  wquant_kernel<<<dim3(1024), 256, 0, stream>>>(w_fc1, (long)8192 * 2048 / 4, acc + 2, 16777216.f, wq_fc1, 11);
  wquant_kernel<<<dim3(1024), 256, 0, stream>>>(w_fc2, (long)2048 * 8192 / 4, acc + 3, 16777216.f, wq_fc2, 13);

  ln_quant_kernel<<<4096, 256, 0, stream>>>(x, g1, b1, q8, invs);
  gemm_i8_big<0><<<16 * 24, 512, 0, stream>>>(q8, wq_qkv, 6144, 2048, acc + 0, 12582912.f, invs, nullptr, qkvh);
  fattn_kernel<<<512, 512, 0, stream>>>(qkvh, obuf);
  row_quant_kernel<2048><<<4096, 256, 0, stream>>>(obuf, q8, invs);
  gemm_i8<1><<<16 * 32, 256, 0, stream>>>(q8, wq_proj, 2048, 2048, acc + 1, 4194304.f, invs, x, x2);
  ln_quant_kernel<<<4096, 256, 0, stream>>>(x2, g2, b2, q8, invs);
  gemm_i8_big<2><<<16 * 32, 512, 0, stream>>>(q8, wq_fc1, 8192, 2048, acc + 2, 16777216.f, invs, nullptr, qkvh);
  row_quant_kernel<8192><<<4096, 256, 0, stream>>>(qkvh, q8, invs);
  gemm_i8<1><<<16 * 32, 256, 0, stream>>>(q8, wq_fc2, 2048, 8192, acc + 3, 16777216.f, invs, x2, (float*)d_out);
}

// Round 4
// 763.931 us; speedup vs baseline: 1.0028x; 1.0028x over previous
//
#include <hip/hip_runtime.h>
#include <cstdint>

#define DEVI __device__ __forceinline__

typedef int v4i __attribute__((ext_vector_type(4)));
typedef short v8s __attribute__((ext_vector_type(8)));
typedef float v4f __attribute__((ext_vector_type(4)));

// ---------- bf16 helpers (manual, RNE) ----------
DEVI float bf_lo(unsigned u) { return __uint_as_float(u << 16); }
DEVI float bf_hi(unsigned u) { return __uint_as_float(u & 0xffff0000u); }
DEVI float bf2f(unsigned short h) { return __uint_as_float(((unsigned)h) << 16); }
DEVI unsigned short f2bf(float f) {
  unsigned u = __float_as_uint(f);
  u += 0x7fffu + ((u >> 16) & 1u);
  return (unsigned short)(u >> 16);
}

// ---------- async global->LDS, 16B per lane (lane i lands at base + i*16) ----------
DEVI void async_copy16(void* l, const void* g) {
  __builtin_amdgcn_global_load_lds((const __attribute__((address_space(1))) void*)g,
                                   (__attribute__((address_space(3))) void*)l,
                                   16, 0, 0);
}

// ---------- wave (64-lane) reductions ----------
DEVI float wave_sum(float v) {
#pragma unroll
  for (int o = 32; o > 0; o >>= 1) v += __shfl_xor(v, o, 64);
  return v;
}
DEVI float wave_max(float v) {
#pragma unroll
  for (int o = 32; o > 0; o >>= 1) v = fmaxf(v, __shfl_xor(v, o, 64));
  return v;
}

// ---------- fused per-tensor sum(|w|), 4 tensors in one launch (tensor = blockIdx&3) ----------
__global__ __launch_bounds__(256) void absum4_kernel(const float* __restrict__ w0,
                                                     const float* __restrict__ w1,
                                                     const float* __restrict__ w2,
                                                     const float* __restrict__ w3,
                                                     float* __restrict__ acc) {
  int t = blockIdx.x & 3;
  int bid = blockIdx.x >> 2;
  int nb = gridDim.x >> 2;
  const float* w = t == 0 ? w0 : t == 1 ? w1 : t == 2 ? w2 : w3;
  long n = t == 0 ? 12582912L : t == 1 ? 4194304L : 16777216L;
  long stride = (long)nb * 1024;
  float s = 0.f;
  for (long i = ((long)bid * 256 + threadIdx.x) * 4; i < n; i += stride) {
    float4 v = *(const float4*)(w + i);
    s += fabsf(v.x) + fabsf(v.y) + fabsf(v.z) + fabsf(v.w);
  }
  s = wave_sum(s);
  __shared__ float sc[4];
  int tid = threadIdx.x;
  if ((tid & 63) == 0) sc[tid >> 6] = s;
  __syncthreads();
  if (tid == 0) atomicAdd(acc + t, sc[0] + sc[1] + sc[2] + sc[3]);
}

// ---------- fused ternary weight quant (4 tensors), MFMA-fragment-major packed layout ----------
__global__ __launch_bounds__(256) void wquant4_kernel(const float* __restrict__ w0,
                                                      const float* __restrict__ w1,
                                                      const float* __restrict__ w2,
                                                      const float* __restrict__ w3,
                                                      const float* __restrict__ acc,
                                                      signed char* __restrict__ o0,
                                                      signed char* __restrict__ o1,
                                                      signed char* __restrict__ o2,
                                                      signed char* __restrict__ o3) {
  int t = blockIdx.x & 3;
  int bid = blockIdx.x >> 2;
  int nb = gridDim.x >> 2;
  const float* w;
  signed char* out;
  long n4;
  float cnt;
  int kshift;
  if (t == 0)      { w = w0; out = o0; n4 = 3145728L; cnt = 12582912.f; kshift = 11; }
  else if (t == 1) { w = w1; out = o1; n4 = 1048576L; cnt = 4194304.f;  kshift = 11; }
  else if (t == 2) { w = w2; out = o2; n4 = 4194304L; cnt = 16777216.f; kshift = 11; }
  else             { w = w3; out = o3; n4 = 4194304L; cnt = 16777216.f; kshift = 13; }
  float wsv = fmaxf(acc[t] / cnt, 1e-5f);
  float inv = 1.0f / wsv;
  int K = 1 << kshift;
  long stride = (long)nb * 256;
  for (long i = (long)bid * 256 + threadIdx.x; i < n4; i += stride) {
    float4 v = *(const float4*)(w + i * 4);
    int q0 = max(-1, min(1, (int)rintf(v.x * inv)));
    int q1 = max(-1, min(1, (int)rintf(v.y * inv)));
    int q2 = max(-1, min(1, (int)rintf(v.z * inv)));
    int q3 = max(-1, min(1, (int)rintf(v.w * inv)));
    unsigned r = (q0 & 0xff) | ((q1 & 0xff) << 8) | ((q2 & 0xff) << 16) | ((q3 & 0xff) << 24);
    long flat = i * 4;
    int n = (int)(flat >> kshift);
    int k = (int)(flat & (K - 1));
    long off = ((long)(n >> 4) * (K >> 6) + (k >> 6)) * 1024 +
               (((k >> 4) & 3) * 16 + (n & 15)) * 16 + (k & 15);
    *(unsigned*)(out + off) = r;
  }
}

// ---------- fused LayerNorm + per-token absmax int8 quant (C=2048, 1 block/row) ----------
__global__ __launch_bounds__(256) void ln_quant_kernel(const float* __restrict__ x,
                                                       const float* __restrict__ g,
                                                       const float* __restrict__ b,
                                                       signed char* __restrict__ q,
                                                       float* __restrict__ inv_s) {
  int row = blockIdx.x, tid = threadIdx.x;
  const float4* xr = (const float4*)(x + (long)row * 2048);
  float4 a0 = xr[tid * 2], a1 = xr[tid * 2 + 1];
  float xv[8] = {a0.x, a0.y, a0.z, a0.w, a1.x, a1.y, a1.z, a1.w};
  float s = 0.f, s2 = 0.f;
#pragma unroll
  for (int e = 0; e < 8; ++e) { s += xv[e]; s2 += xv[e] * xv[e]; }
  s = wave_sum(s); s2 = wave_sum(s2);
  __shared__ float sc[8];
  if ((tid & 63) == 0) { sc[tid >> 6] = s; sc[4 + (tid >> 6)] = s2; }
  __syncthreads();
  float mean = (sc[0] + sc[1] + sc[2] + sc[3]) * (1.f / 2048.f);
  float var = (sc[4] + sc[5] + sc[6] + sc[7]) * (1.f / 2048.f) - mean * mean;
  float rs = 1.0f / sqrtf(var + 1e-5f);
  float4 g0 = ((const float4*)g)[tid * 2], g1v = ((const float4*)g)[tid * 2 + 1];
  float4 b0 = ((const float4*)b)[tid * 2], b1v = ((const float4*)b)[tid * 2 + 1];
  float gv[8] = {g0.x, g0.y, g0.z, g0.w, g1v.x, g1v.y, g1v.z, g1v.w};
  float bv[8] = {b0.x, b0.y, b0.z, b0.w, b1v.x, b1v.y, b1v.z, b1v.w};
  float y[8];
  float am = 0.f;
#pragma unroll
  for (int e = 0; e < 8; ++e) {
    y[e] = (xv[e] - mean) * rs * gv[e] + bv[e];
    am = fmaxf(am, fabsf(y[e]));
  }
  am = wave_max(am);
  __syncthreads();
  if ((tid & 63) == 0) sc[tid >> 6] = am;
  __syncthreads();
  am = fmaxf(fmaxf(sc[0], sc[1]), fmaxf(sc[2], sc[3]));
  float c = fmaxf(am, 1e-5f);
  float xs = 127.0f / c;
  union { signed char c8[8]; int2 v; } u;
#pragma unroll
  for (int e = 0; e < 8; ++e) {
    int t = (int)rintf(y[e] * xs);
    u.c8[e] = (signed char)max(-128, min(127, t));
  }
  ((int2*)(q + (long)row * 2048))[tid] = u.v;
  if (tid == 0) inv_s[row] = c * (1.0f / 127.0f);
}

// ---------- per-row absmax int8 quant from bf16 rows (R = 2048 or 8192) ----------
template <int R>
__global__ __launch_bounds__(256) void row_quant_kernel(const unsigned short* __restrict__ in,
                                                        signed char* __restrict__ q,
                                                        float* __restrict__ inv_s) {
  constexpr int V = R / 2048;
  int row = blockIdx.x, tid = threadIdx.x;
  const uint4* p = (const uint4*)(in + (long)row * R);
  float y[V * 8];
  float am = 0.f;
#pragma unroll
  for (int v = 0; v < V; ++v) {
    uint4 d = p[tid * V + v];
    unsigned xw[4] = {d.x, d.y, d.z, d.w};
#pragma unroll
    for (int k = 0; k < 4; ++k) {
      y[v * 8 + k * 2] = bf_lo(xw[k]);
      y[v * 8 + k * 2 + 1] = bf_hi(xw[k]);
    }
  }
#pragma unroll
  for (int e = 0; e < V * 8; ++e) am = fmaxf(am, fabsf(y[e]));
  am = wave_max(am);
  __shared__ float sc[4];
  if ((tid & 63) == 0) sc[tid >> 6] = am;
  __syncthreads();
  am = fmaxf(fmaxf(sc[0], sc[1]), fmaxf(sc[2], sc[3]));
  float c = fmaxf(am, 1e-5f);
  float xs = 127.0f / c;
  signed char* qr = q + (long)row * R;
#pragma unroll
  for (int v = 0; v < V; ++v) {
    union { signed char c8[8]; long l; } u;
#pragma unroll
    for (int k = 0; k < 8; ++k) {
      int t = (int)rintf(y[v * 8 + k] * xs);
      u.c8[k] = (signed char)max(-128, min(127, t));
    }
    ((long*)qr)[tid * V + v] = u.l;
  }
  if (tid == 0) inv_s[row] = c * (1.0f / 127.0f);
}

// ---------- int8 MFMA GEMM (128x128 tile, 2-phase) — kept for N=2048 gemms ----------
template <int EPI>
__global__ __launch_bounds__(256)
void gemm_i8(const signed char* __restrict__ A, const signed char* __restrict__ Bp,
             int N, int K, const float* __restrict__ wacc, float wcount,
             const float* __restrict__ inv_s, const float* __restrict__ res,
             void* __restrict__ outp) {
  __shared__ signed char As[2][128 * 128];
  int tid = threadIdx.x;
  int idx = blockIdx.x;
  int r8 = idx & 7, rest = idx >> 3;
  int mb = rest & 31;
  int nb = (rest >> 5) * 8 + r8;
  int m0 = mb * 128, n0 = nb * 128;
  int w = tid >> 6, lane = tid & 63;
  int wm = (w >> 1) * 64, wn = (w & 1) * 64;
  int lr = lane & 15, q = lane >> 4;

  v4i acc[4][4] = {};

  int srow = w * 32 + (lane >> 3);
  int scol = (lane & 7) ^ ((lane >> 3) & 7);
  const signed char* ga = A + (long)(m0 + srow) * K + scol * 16;

  int nkb = K >> 7;
  const signed char* gbp[4];
#pragma unroll
  for (int t = 0; t < 4; ++t) {
    int ntile = (n0 >> 4) + (w & 1) * 4 + t;
    gbp[t] = Bp + (long)ntile * (K >> 6) * 1024 + lane * 16;
  }

  v4i bf_cur[2][4], bf_nxt[2][4];
#pragma unroll
  for (int i = 0; i < 4; ++i)
    async_copy16(&As[0][(w * 256 + i * 64) * 16], ga + i * 8 * K);
#pragma unroll
  for (int s = 0; s < 2; ++s)
#pragma unroll
    for (int t = 0; t < 4; ++t) bf_cur[s][t] = *(const v4i*)(gbp[t] + s * 1024);
  __syncthreads();

  int buf = 0;
  for (int kb = 0; kb < nkb; ++kb) {
    if (kb + 1 < nkb) {
#pragma unroll
      for (int i = 0; i < 4; ++i)
        async_copy16(&As[buf ^ 1][(w * 256 + i * 64) * 16], ga + i * 8 * K + (kb + 1) * 128);
#pragma unroll
      for (int s = 0; s < 2; ++s)
#pragma unroll
        for (int t = 0; t < 4; ++t)
          bf_nxt[s][t] = *(const v4i*)(gbp[t] + ((kb + 1) * 2 + s) * 1024);
    }
#pragma unroll
    for (int s = 0; s < 2; ++s) {
      v4i af[4];
#pragma unroll
      for (int i = 0; i < 4; ++i) {
        int row = wm + i * 16 + lr;
        af[i] = *(const v4i*)(&As[buf][(row * 8 + ((s * 4 + q) ^ (lr & 7))) * 16]);
      }
#pragma unroll
      for (int i = 0; i < 4; ++i)
#pragma unroll
        for (int j = 0; j < 4; ++j)
          acc[i][j] = __builtin_amdgcn_mfma_i32_16x16x64_i8(af[i], bf_cur[s][j], acc[i][j], 0, 0, 0);
    }
    __syncthreads();
    if (kb + 1 < nkb) {
#pragma unroll
      for (int s = 0; s < 2; ++s)
#pragma unroll
        for (int t = 0; t < 4; ++t) bf_cur[s][t] = bf_nxt[s][t];
    }
    buf ^= 1;
  }

  float wsv = fmaxf(wacc[0] / wcount, 1e-5f);
#pragma unroll
  for (int i = 0; i < 4; ++i) {
    int rowbase = m0 + wm + i * 16 + (lane >> 4) * 4;
#pragma unroll
    for (int r = 0; r < 4; ++r) {
      int row = rowbase + r;
      float s = wsv * inv_s[row];
#pragma unroll
      for (int j = 0; j < 4; ++j) {
        int col = n0 + wn + j * 16 + (lane & 15);
        long off = (long)row * N + col;
        float v = (float)acc[i][j][r] * s;
        if constexpr (EPI == 0) {
          ((unsigned short*)outp)[off] = f2bf(v);
        } else if constexpr (EPI == 1) {
          ((float*)outp)[off] = v + res[off];
        } else {
          float gvv = 0.5f * v * (1.0f + erff(v * 0.70710678118654752f));
          ((unsigned short*)outp)[off] = f2bf(gvv);
        }
      }
    }
  }
}

// ========== int8 MFMA GEMM "big": 256x256 tile, BK=128, 8 waves, phase-split + ds-prefetch ==========
// R3 structure + register-level ds_read pipelining one phase ahead (counted lgkmcnt(4), never
// full-drain except phase 3). Phase 0 issues 8 ds_reads (its own + phase 1's); phases 1-2 issue the
// next phase's 4; phase 3 issues none. All reads of a freshly staged LDS buffer happen strictly
// after the post-vmcnt(8) barrier (cross-wave staging safety). vm ops remain asm-pinned:
// per-iter order [4 staging][4 B][4 B]; phase0 waits vmcnt(4) (prev B drained, staging in flight),
// phase3 tail vmcnt(8) (staging drained, next B in flight). Last iteration peeled.
#define GIB_DS(AF, MLO, RBUF)                                                           \
  _Pragma("unroll") for (int j = 0; j < 4; ++j) {                                       \
    int m = (MLO) + (j >> 1), kc = j & 1;                                               \
    int row = wm + m * 16 + lr;                                                         \
    AF[j] = *(const v4i*)(&As[(RBUF)][(row * 8 + ((kc * 4 + q) ^ (lr & 7))) * 16]);     \
  }

#define GIB_MM(AF, MLO, BFC)                                                            \
  _Pragma("unroll") for (int j2 = 0; j2 < 2; ++j2)                                      \
    _Pragma("unroll") for (int t = 0; t < 4; ++t)                                       \
      _Pragma("unroll") for (int kc = 0; kc < 2; ++kc)                                  \
        acc[(MLO) + j2][t] = __builtin_amdgcn_mfma_i32_16x16x64_i8(                     \
            AF[j2 * 2 + kc], BFC[kc][t], acc[(MLO) + j2][t], 0, 0, 0);

#define GIB_PH(DSISSUE, VMISSUE, WAITSTR, MMPART, TAIL)                                 \
  {                                                                                     \
    DSISSUE                                                                             \
    __builtin_amdgcn_sched_barrier(0);                                                  \
    VMISSUE                                                                             \
    __builtin_amdgcn_sched_barrier(0);                                                  \
    __builtin_amdgcn_s_barrier();                                                       \
    asm volatile(WAITSTR ::: "memory");                                                 \
    __builtin_amdgcn_sched_barrier(0);                                                  \
    __builtin_amdgcn_s_setprio(1);                                                      \
    MMPART                                                                              \
    __builtin_amdgcn_s_setprio(0);                                                      \
    __builtin_amdgcn_sched_barrier(0);                                                  \
    TAIL                                                                                \
    __builtin_amdgcn_s_barrier();                                                       \
  }

#define GIB_STAGE(RBD)                                                                  \
  _Pragma("unroll") for (int i = 0; i < 4; ++i)                                         \
    async_copy16(&As[(RBD)][(w * 256 + i * 64) * 16],                                   \
                 ga + (long)i * 8 * K + (kb + 1) * 128);

#define GIB_LOADB(DST, HALF)                                                            \
  _Pragma("unroll") for (int t = 0; t < 4; ++t)                                         \
    asm volatile("global_load_dwordx4 %0, %1, off"                                      \
                 : "=v"(DST[HALF][t])                                                   \
                 : "v"(gbp[t] + (long)((kb + 1) * 2 + (HALF)) * 1024)                   \
                 : "memory");

#define GIB_VMTAIL                                                                      \
  asm volatile("s_waitcnt vmcnt(8)" ::: "memory");                                      \
  __builtin_amdgcn_sched_barrier(0);

#define GIB_ITER_MAIN(RB, BFC, BFN)                                                     \
  {                                                                                     \
    GIB_PH(GIB_DS(afA, 0, RB) GIB_DS(afB, 2, RB), GIB_STAGE((RB) ^ 1),                  \
           "s_waitcnt vmcnt(4) lgkmcnt(4)", GIB_MM(afA, 0, BFC), )                      \
    GIB_PH(GIB_DS(afA, 4, RB), GIB_LOADB(BFN, 0),                                       \
           "s_waitcnt lgkmcnt(4)", GIB_MM(afB, 2, BFC), )                               \
    GIB_PH(GIB_DS(afB, 6, RB), GIB_LOADB(BFN, 1),                                       \
           "s_waitcnt lgkmcnt(4)", GIB_MM(afA, 4, BFC), )                               \
    GIB_PH(, , "s_waitcnt lgkmcnt(0)", GIB_MM(afB, 6, BFC), GIB_VMTAIL)                 \
  }

#define GIB_ITER_LAST(RB, BFC)                                                          \
  {                                                                                     \
    GIB_PH(GIB_DS(afA, 0, RB) GIB_DS(afB, 2, RB), ,                                     \
           "s_waitcnt vmcnt(0) lgkmcnt(4)", GIB_MM(afA, 0, BFC), )                      \
    GIB_PH(GIB_DS(afA, 4, RB), , "s_waitcnt lgkmcnt(4)", GIB_MM(afB, 2, BFC), )         \
    GIB_PH(GIB_DS(afB, 6, RB), , "s_waitcnt lgkmcnt(4)", GIB_MM(afA, 4, BFC), )         \
    GIB_PH(, , "s_waitcnt lgkmcnt(0)", GIB_MM(afB, 6, BFC), )                           \
  }

template <int EPI>
__global__ __launch_bounds__(512, 2)
void gemm_i8_big(const signed char* __restrict__ A, const signed char* __restrict__ Bp,
                 int N, int K, const float* __restrict__ wacc, float wcount,
                 const float* __restrict__ inv_s, const float* __restrict__ res,
                 void* __restrict__ outp) {
  __shared__ signed char As[2][256 * 128];
  int tid = threadIdx.x;
  // decode: idx = (n&7) + 8*((n>>3)*16 + m)   [NB % 8 == 0, MB = 16]
  int idx = blockIdx.x;
  int r8 = idx & 7, rest = idx >> 3;
  int mb = rest & 15;
  int nb = (rest >> 4) * 8 + r8;
  int m0 = mb * 256, n0 = nb * 256;
  int w = tid >> 6, lane = tid & 63;
  int wm = (w >> 2) * 128, wn = (w & 3) * 64;
  int lr = lane & 15, q = lane >> 4;

  v4i acc[8][4] = {};

  // A staging: 256 rows x 8 chunks(16B); wave w covers rows [w*32, w*32+32), 4 instrs.
  // LDS chunk u = row*8 + (cg ^ (row&7)); lane-linear dest (w*256 + i*64 + lane)*16.
  int srow = w * 32 + (lane >> 3);
  int scol = (lane & 7) ^ ((lane >> 3) & 7);
  const signed char* ga = A + (long)(m0 + srow) * K + scol * 16;

  int nkt = K >> 7;  // 16 for K=2048 (even, >= 4; loop below relies on this)
  const signed char* gbp[4];
#pragma unroll
  for (int t = 0; t < 4; ++t) {
    int ntile = ((n0 + wn) >> 4) + t;
    gbp[t] = Bp + (long)ntile * (K >> 6) * 1024 + lane * 16;
  }

  v4i bfA[2][4], bfB[2][4];
  v4i afA[4], afB[4];
  // prologue: stage A tile 0 (4 vm), then B frags tile 0 (8 vm, asm-pinned order).
#pragma unroll
  for (int i = 0; i < 4; ++i)
    async_copy16(&As[0][(w * 256 + i * 64) * 16], ga + (long)i * 8 * K);
  __builtin_amdgcn_sched_barrier(0);
#pragma unroll
  for (int s = 0; s < 2; ++s)
#pragma unroll
    for (int t = 0; t < 4; ++t)
      asm volatile("global_load_dwordx4 %0, %1, off"
                   : "=v"(bfA[s][t]) : "v"(gbp[t] + (long)s * 1024) : "memory");
  __builtin_amdgcn_sched_barrier(0);
  asm volatile("s_waitcnt vmcnt(8)" ::: "memory");  // tile-0 staging landed; B in flight
  __builtin_amdgcn_sched_barrier(0);
  __builtin_amdgcn_s_barrier();

  for (int kb2 = 0; kb2 < nkt - 2; kb2 += 2) {
    { int kb = kb2;     GIB_ITER_MAIN(0, bfA, bfB) }
    { int kb = kb2 + 1; GIB_ITER_MAIN(1, bfB, bfA) }
  }
  { int kb = nkt - 2; GIB_ITER_MAIN(0, bfA, bfB) }
  GIB_ITER_LAST(1, bfB)

  float wsv = fmaxf(wacc[0] / wcount, 1e-5f);
#pragma unroll
  for (int m = 0; m < 8; ++m) {
    int rowbase = m0 + wm + m * 16 + q * 4;
#pragma unroll
    for (int r = 0; r < 4; ++r) {
      int row = rowbase + r;
      float s = wsv * inv_s[row];
#pragma unroll
      for (int j = 0; j < 4; ++j) {
        int col = n0 + wn + j * 16 + lr;
        long off = (long)row * N + col;
        float v = (float)acc[m][j][r] * s;
        if constexpr (EPI == 0) {
          ((unsigned short*)outp)[off] = f2bf(v);
        } else if constexpr (EPI == 1) {
          ((float*)outp)[off] = v + res[off];
        } else {
          float gvv = 0.5f * v * (1.0f + erff(v * 0.70710678118654752f));
          ((unsigned short*)outp)[off] = f2bf(gvv);
        }
      }
    }
  }
}

// ================== MFMA flash attention v2 (verified round 1) ==================
DEVI int sigma_k(int y) {
  return (y & 35) | (((y >> 3) & 1) << 4) | (((y >> 2) & 1) << 3) | (((y >> 4) & 1) << 2);
}

DEVI void stage_k(const unsigned short* kbase_g, int k0, char* ks, int w, int lane) {
#pragma unroll
  for (int i = 0; i < 2; ++i) {
    int c = i * 512 + w * 64 + lane;
    int key = c >> 4;
    int dch = (c & 15) ^ (key & 15);
    async_copy16(ks + (i * 512 + w * 64) * 16,
                 kbase_g + (long)(k0 + sigma_k(key)) * 6144 + dch * 8);
  }
}

DEVI void load_v(const unsigned short* vbase_g, int k0, int kg, int dg, uint2* lv) {
#pragma unroll
  for (int i = 0; i < 4; ++i)
    lv[i] = *(const uint2*)(vbase_g + (long)(k0 + kg * 4 + i) * 6144 + dg * 4);
}

DEVI void repack_v(const uint2* lv, unsigned short* vt, int kg, int dg) {
#pragma unroll
  for (int jd = 0; jd < 4; ++jd) {
    union { unsigned short s[4]; unsigned long long u; } pk;
#pragma unroll
    for (int i = 0; i < 4; ++i) {
      unsigned word = (jd < 2) ? lv[i].x : lv[i].y;
      pk.s[i] = (unsigned short)((jd & 1) ? (word >> 16) : (word & 0xffffu));
    }
    *(unsigned long long*)(vt + (dg * 4 + jd) * 72 + kg * 4) = pk.u;
  }
}

__global__ __launch_bounds__(512, 4)
void fattn_kernel(const unsigned short* __restrict__ qkv, unsigned short* __restrict__ out) {
  constexpr int VROW = 72;
  __shared__ __align__(16) char Ks[2][16384];
  __shared__ __align__(16) unsigned short Vt[2][128 * VROW];

  int tid = threadIdx.x;
  int w = tid >> 6, lane = tid & 63;
  int l = lane & 15, q = lane >> 4;
  int idx = blockIdx.x;
  int r8 = idx & 7, rest = idx >> 3;
  int qt = rest & 15;
  int bh = (rest >> 4) * 8 + r8;
  int bb = bh >> 4, hh = bh & 15;
  const unsigned short* base = qkv + (long)bb * 2048 * 6144;
  int q0 = qt * 128;

  v8s aq[4];
  {
    const unsigned short* qrow = base + (long)(q0 + w * 16 + l) * 6144 + hh * 128;
#pragma unroll
    for (int kf = 0; kf < 4; ++kf) aq[kf] = *(const v8s*)(qrow + kf * 32 + q * 8);
  }

  v4f oacc[8] = {};
  float mrow = -1e30f, lrow = 0.f;

  const unsigned short* kbase_g = base + 2048 + hh * 128;
  const unsigned short* vbase_g = base + 4096 + hh * 128;
  int kg = tid & 15, dg = tid >> 4;
  constexpr float SC = 0.08838834764831845f;

  stage_k(kbase_g, 0, Ks[0], w, lane);
  uint2 lv[4];
  load_v(vbase_g, 0, kg, dg, lv);
  repack_v(lv, Vt[0], kg, dg);
  __syncthreads();

  for (int kt = 0; kt < 32; ++kt) {
    const char* ksc = Ks[kt & 1];
    const unsigned short* vtc = Vt[kt & 1];
    bool more = kt < 31;
    if (more) {
      stage_k(kbase_g, (kt + 1) * 64, Ks[(kt + 1) & 1], w, lane);
      load_v(vbase_g, (kt + 1) * 64, kg, dg, lv);
    }

    v4f sacc[4] = {};
#pragma unroll
    for (int kf = 0; kf < 4; ++kf) {
#pragma unroll
      for (int t = 0; t < 4; ++t) {
        int ch = (t * 16 + l) * 16 + ((kf * 4 + q) ^ l);
        v8s bk = *(const v8s*)(ksc + ch * 16);
        sacc[t] = __builtin_amdgcn_mfma_f32_16x16x32_bf16(bk, aq[kf], sacc[t], 0, 0, 0);
      }
    }

    float rm = -1e30f;
#pragma unroll
    for (int t = 0; t < 4; ++t)
#pragma unroll
      for (int r = 0; r < 4; ++r) rm = fmaxf(rm, sacc[t][r]);
    rm *= SC;
    rm = fmaxf(rm, __shfl_xor(rm, 16, 64));
    rm = fmaxf(rm, __shfl_xor(rm, 32, 64));
    float mnew = fmaxf(mrow, rm);
    if (__any(mnew - mrow > 8.0f)) {
      float alpha = __expf(mrow - mnew);
      mrow = mnew;
      lrow *= alpha;
#pragma unroll
      for (int r = 0; r < 4; ++r) {
        float ao = __shfl(alpha, q * 4 + r, 64);
#pragma unroll
        for (int t = 0; t < 8; ++t) oacc[t][r] *= ao;
      }
    }
    float rs = 0.f;
#pragma unroll
    for (int t = 0; t < 4; ++t)
#pragma unroll
      for (int r = 0; r < 4; ++r) {
        float pv = __expf(fmaf(sacc[t][r], SC, -mrow));
        sacc[t][r] = pv;
        rs += pv;
      }
    rs += __shfl_xor(rs, 16, 64);
    rs += __shfl_xor(rs, 32, 64);
    lrow += rs;

    union { unsigned u[4]; v8s s; } pa[2];
#pragma unroll
    for (int s2 = 0; s2 < 2; ++s2)
#pragma unroll
      for (int j2 = 0; j2 < 4; ++j2) {
        int tt = s2 * 2 + (j2 >> 1);
        int r0 = (j2 & 1) * 2;
        unsigned wrd;
        asm("v_cvt_pk_bf16_f32 %0, %1, %2"
            : "=v"(wrd) : "v"(sacc[tt][r0]), "v"(sacc[tt][r0 + 1]));
        pa[s2].u[j2] = wrd;
      }

#pragma unroll
    for (int s2 = 0; s2 < 2; ++s2) {
#pragma unroll
      for (int t = 0; t < 8; ++t) {
        v8s bv = *(const v8s*)(vtc + (t * 16 + l) * VROW + s2 * 32 + q * 8);
        oacc[t] = __builtin_amdgcn_mfma_f32_16x16x32_bf16(pa[s2].s, bv, oacc[t], 0, 0, 0);
      }
    }

    if (more) repack_v(lv, Vt[(kt + 1) & 1], kg, dg);
    __syncthreads();
  }

#pragma unroll
  for (int r = 0; r < 4; ++r) {
    float lr = __shfl(lrow, q * 4 + r, 64);
    float inv = 1.0f / lr;
    long grow = (long)bb * 2048 + q0 + w * 16 + q * 4 + r;
    unsigned short* orow = out + grow * 2048 + hh * 128;
#pragma unroll
    for (int t = 0; t < 8; ++t) orow[t * 16 + l] = f2bf(oacc[t][r] * inv);
  }
}

extern "C" void kernel_launch(void* const* d_in, const int* in_sizes, int n_in,
                              void* d_out, int out_size, void* d_ws, size_t ws_size,
                              hipStream_t stream) {
  (void)in_sizes; (void)n_in; (void)out_size; (void)ws_size;
  const float* x      = (const float*)d_in[0];
  const float* w_qkv  = (const float*)d_in[1];
  const float* w_proj = (const float*)d_in[2];
  const float* w_fc1  = (const float*)d_in[3];
  const float* w_fc2  = (const float*)d_in[4];
  const float* g1 = (const float*)d_in[5];
  const float* b1 = (const float*)d_in[6];
  const float* g2 = (const float*)d_in[7];
  const float* b2 = (const float*)d_in[8];

  char* wsb = (char*)d_ws;
  float* acc = (float*)wsb;
  size_t off = 256;
  signed char* q8 = (signed char*)(wsb + off);       off += (size_t)4096 * 8192;
  float* invs = (float*)(wsb + off);                 off += 16384;
  signed char* wq_qkv = (signed char*)(wsb + off);   off += (size_t)6144 * 2048;
  signed char* wq_proj = (signed char*)(wsb + off);  off += (size_t)2048 * 2048;
  signed char* wq_fc1 = (signed char*)(wsb + off);   off += (size_t)8192 * 2048;
  signed char* wq_fc2 = (signed char*)(wsb + off);   off += (size_t)2048 * 8192;
  unsigned short* qkvh = (unsigned short*)(wsb + off); off += (size_t)4096 * 8192 * 2;
  unsigned short* obuf = (unsigned short*)(wsb + off); off += (size_t)4096 * 2048 * 2;
  float* x2 = (float*)(wsb + off);                   off += (size_t)4096 * 2048 * 4;

  hipMemsetAsync(acc, 0, 256, stream);

  absum4_kernel<<<4096, 256, 0, stream>>>(w_qkv, w_proj, w_fc1, w_fc2, acc);
  wquant4_kernel<<<4096, 256, 0, stream>>>(w_qkv, w_proj, w_fc1, w_fc2, acc,
                                           wq_qkv, wq_proj, wq_fc1, wq_fc2);

  ln_quant_kernel<<<4096, 256, 0, stream>>>(x, g1, b1, q8, invs);
  gemm_i8_big<0><<<16 * 24, 512, 0, stream>>>(q8, wq_qkv, 6144, 2048, acc + 0, 12582912.f, invs, nullptr, qkvh);
  fattn_kernel<<<512, 512, 0, stream>>>(qkvh, obuf);
  row_quant_kernel<2048><<<4096, 256, 0, stream>>>(obuf, q8, invs);
  gemm_i8<1><<<16 * 32, 256, 0, stream>>>(q8, wq_proj, 2048, 2048, acc + 1, 4194304.f, invs, x, x2);
  ln_quant_kernel<<<4096, 256, 0, stream>>>(x2, g2, b2, q8, invs);
  gemm_i8_big<2><<<16 * 32, 512, 0, stream>>>(q8, wq_fc1, 8192, 2048, acc + 2, 16777216.f, invs, nullptr, qkvh);
  row_quant_kernel<8192><<<4096, 256, 0, stream>>>(qkvh, q8, invs);
  gemm_i8<1><<<16 * 32, 256, 0, stream>>>(q8, wq_fc2, 2048, 8192, acc + 3, 16777216.f, invs, x2, (float*)d_out);
}

// Round 5
// 722.983 us; speedup vs baseline: 1.0596x; 1.0566x over previous
//
#include <hip/hip_runtime.h>
#include <cstdint>

#define DEVI __device__ __forceinline__

typedef int v4i __attribute__((ext_vector_type(4)));
typedef short v8s __attribute__((ext_vector_type(8)));
typedef float v4f __attribute__((ext_vector_type(4)));

// ---------- bf16 helpers (manual, RNE) ----------
DEVI float bf_lo(unsigned u) { return __uint_as_float(u << 16); }
DEVI float bf_hi(unsigned u) { return __uint_as_float(u & 0xffff0000u); }
DEVI float bf2f(unsigned short h) { return __uint_as_float(((unsigned)h) << 16); }
DEVI unsigned short f2bf(float f) {
  unsigned u = __float_as_uint(f);
  u += 0x7fffu + ((u >> 16) & 1u);
  return (unsigned short)(u >> 16);
}

// ---------- fast GELU (A&S 7.1.26 erf, |err|<=1.5e-7; quant step ~0.1 -> invisible) ----------
DEVI float fast_gelu(float v) {
  float xx = v * 0.70710678118654752f;
  float ax = fabsf(xx);
  float t = __builtin_amdgcn_rcpf(1.0f + 0.3275911f * ax);
  float p = t * (0.254829592f +
           t * (-0.284496736f +
           t * (1.421413741f +
           t * (-1.453152027f + t * 1.061405429f))));
  float e = __expf(-ax * ax);
  float er = 1.0f - p * e;
  er = copysignf(er, xx);
  return 0.5f * v * (1.0f + er);
}

// ---------- async global->LDS, 16B per lane (lane i lands at base + i*16) ----------
DEVI void async_copy16(void* l, const void* g) {
  __builtin_amdgcn_global_load_lds((const __attribute__((address_space(1))) void*)g,
                                   (__attribute__((address_space(3))) void*)l,
                                   16, 0, 0);
}

// ---------- wave (64-lane) reductions ----------
DEVI float wave_sum(float v) {
#pragma unroll
  for (int o = 32; o > 0; o >>= 1) v += __shfl_xor(v, o, 64);
  return v;
}
DEVI float wave_max(float v) {
#pragma unroll
  for (int o = 32; o > 0; o >>= 1) v = fmaxf(v, __shfl_xor(v, o, 64));
  return v;
}

// ---------- fused per-tensor sum(|w|), 4 tensors in one launch (tensor = blockIdx&3) ----------
__global__ __launch_bounds__(256) void absum4_kernel(const float* __restrict__ w0,
                                                     const float* __restrict__ w1,
                                                     const float* __restrict__ w2,
                                                     const float* __restrict__ w3,
                                                     float* __restrict__ acc) {
  int t = blockIdx.x & 3;
  int bid = blockIdx.x >> 2;
  int nb = gridDim.x >> 2;
  const float* w = t == 0 ? w0 : t == 1 ? w1 : t == 2 ? w2 : w3;
  long n = t == 0 ? 12582912L : t == 1 ? 4194304L : 16777216L;
  long stride = (long)nb * 1024;
  float s = 0.f;
  for (long i = ((long)bid * 256 + threadIdx.x) * 4; i < n; i += stride) {
    float4 v = *(const float4*)(w + i);
    s += fabsf(v.x) + fabsf(v.y) + fabsf(v.z) + fabsf(v.w);
  }
  s = wave_sum(s);
  __shared__ float sc[4];
  int tid = threadIdx.x;
  if ((tid & 63) == 0) sc[tid >> 6] = s;
  __syncthreads();
  if (tid == 0) atomicAdd(acc + t, sc[0] + sc[1] + sc[2] + sc[3]);
}

// ---------- fused ternary weight quant (4 tensors), MFMA-fragment-major packed layout ----------
__global__ __launch_bounds__(256) void wquant4_kernel(const float* __restrict__ w0,
                                                      const float* __restrict__ w1,
                                                      const float* __restrict__ w2,
                                                      const float* __restrict__ w3,
                                                      const float* __restrict__ acc,
                                                      signed char* __restrict__ o0,
                                                      signed char* __restrict__ o1,
                                                      signed char* __restrict__ o2,
                                                      signed char* __restrict__ o3) {
  int t = blockIdx.x & 3;
  int bid = blockIdx.x >> 2;
  int nb = gridDim.x >> 2;
  const float* w;
  signed char* out;
  long n4;
  float cnt;
  int kshift;
  if (t == 0)      { w = w0; out = o0; n4 = 3145728L; cnt = 12582912.f; kshift = 11; }
  else if (t == 1) { w = w1; out = o1; n4 = 1048576L; cnt = 4194304.f;  kshift = 11; }
  else if (t == 2) { w = w2; out = o2; n4 = 4194304L; cnt = 16777216.f; kshift = 11; }
  else             { w = w3; out = o3; n4 = 4194304L; cnt = 16777216.f; kshift = 13; }
  float wsv = fmaxf(acc[t] / cnt, 1e-5f);
  float inv = 1.0f / wsv;
  int K = 1 << kshift;
  long stride = (long)nb * 256;
  for (long i = (long)bid * 256 + threadIdx.x; i < n4; i += stride) {
    float4 v = *(const float4*)(w + i * 4);
    int q0 = max(-1, min(1, (int)rintf(v.x * inv)));
    int q1 = max(-1, min(1, (int)rintf(v.y * inv)));
    int q2 = max(-1, min(1, (int)rintf(v.z * inv)));
    int q3 = max(-1, min(1, (int)rintf(v.w * inv)));
    unsigned r = (q0 & 0xff) | ((q1 & 0xff) << 8) | ((q2 & 0xff) << 16) | ((q3 & 0xff) << 24);
    long flat = i * 4;
    int n = (int)(flat >> kshift);
    int k = (int)(flat & (K - 1));
    long off = ((long)(n >> 4) * (K >> 6) + (k >> 6)) * 1024 +
               (((k >> 4) & 3) * 16 + (n & 15)) * 16 + (k & 15);
    *(unsigned*)(out + off) = r;
  }
}

// ---------- fused LayerNorm + per-token absmax int8 quant (C=2048, 1 block/row) ----------
__global__ __launch_bounds__(256) void ln_quant_kernel(const float* __restrict__ x,
                                                       const float* __restrict__ g,
                                                       const float* __restrict__ b,
                                                       signed char* __restrict__ q,
                                                       float* __restrict__ inv_s) {
  int row = blockIdx.x, tid = threadIdx.x;
  const float4* xr = (const float4*)(x + (long)row * 2048);
  float4 a0 = xr[tid * 2], a1 = xr[tid * 2 + 1];
  float xv[8] = {a0.x, a0.y, a0.z, a0.w, a1.x, a1.y, a1.z, a1.w};
  float s = 0.f, s2 = 0.f;
#pragma unroll
  for (int e = 0; e < 8; ++e) { s += xv[e]; s2 += xv[e] * xv[e]; }
  s = wave_sum(s); s2 = wave_sum(s2);
  __shared__ float sc[8];
  if ((tid & 63) == 0) { sc[tid >> 6] = s; sc[4 + (tid >> 6)] = s2; }
  __syncthreads();
  float mean = (sc[0] + sc[1] + sc[2] + sc[3]) * (1.f / 2048.f);
  float var = (sc[4] + sc[5] + sc[6] + sc[7]) * (1.f / 2048.f) - mean * mean;
  float rs = 1.0f / sqrtf(var + 1e-5f);
  float4 g0 = ((const float4*)g)[tid * 2], g1v = ((const float4*)g)[tid * 2 + 1];
  float4 b0 = ((const float4*)b)[tid * 2], b1v = ((const float4*)b)[tid * 2 + 1];
  float gv[8] = {g0.x, g0.y, g0.z, g0.w, g1v.x, g1v.y, g1v.z, g1v.w};
  float bv[8] = {b0.x, b0.y, b0.z, b0.w, b1v.x, b1v.y, b1v.z, b1v.w};
  float y[8];
  float am = 0.f;
#pragma unroll
  for (int e = 0; e < 8; ++e) {
    y[e] = (xv[e] - mean) * rs * gv[e] + bv[e];
    am = fmaxf(am, fabsf(y[e]));
  }
  am = wave_max(am);
  __syncthreads();
  if ((tid & 63) == 0) sc[tid >> 6] = am;
  __syncthreads();
  am = fmaxf(fmaxf(sc[0], sc[1]), fmaxf(sc[2], sc[3]));
  float c = fmaxf(am, 1e-5f);
  float xs = 127.0f / c;
  union { signed char c8[8]; int2 v; } u;
#pragma unroll
  for (int e = 0; e < 8; ++e) {
    int t = (int)rintf(y[e] * xs);
    u.c8[e] = (signed char)max(-128, min(127, t));
  }
  ((int2*)(q + (long)row * 2048))[tid] = u.v;
  if (tid == 0) inv_s[row] = c * (1.0f / 127.0f);
}

// ---------- per-row absmax int8 quant from bf16 rows (R = 2048 or 8192) ----------
template <int R>
__global__ __launch_bounds__(256) void row_quant_kernel(const unsigned short* __restrict__ in,
                                                        signed char* __restrict__ q,
                                                        float* __restrict__ inv_s) {
  constexpr int V = R / 2048;
  int row = blockIdx.x, tid = threadIdx.x;
  const uint4* p = (const uint4*)(in + (long)row * R);
  float y[V * 8];
  float am = 0.f;
#pragma unroll
  for (int v = 0; v < V; ++v) {
    uint4 d = p[tid * V + v];
    unsigned xw[4] = {d.x, d.y, d.z, d.w};
#pragma unroll
    for (int k = 0; k < 4; ++k) {
      y[v * 8 + k * 2] = bf_lo(xw[k]);
      y[v * 8 + k * 2 + 1] = bf_hi(xw[k]);
    }
  }
#pragma unroll
  for (int e = 0; e < V * 8; ++e) am = fmaxf(am, fabsf(y[e]));
  am = wave_max(am);
  __shared__ float sc[4];
  if ((tid & 63) == 0) sc[tid >> 6] = am;
  __syncthreads();
  am = fmaxf(fmaxf(sc[0], sc[1]), fmaxf(sc[2], sc[3]));
  float c = fmaxf(am, 1e-5f);
  float xs = 127.0f / c;
  signed char* qr = q + (long)row * R;
#pragma unroll
  for (int v = 0; v < V; ++v) {
    union { signed char c8[8]; long l; } u;
#pragma unroll
    for (int k = 0; k < 8; ++k) {
      int t = (int)rintf(y[v * 8 + k] * xs);
      u.c8[k] = (signed char)max(-128, min(127, t));
    }
    ((long*)qr)[tid * V + v] = u.l;
  }
  if (tid == 0) inv_s[row] = c * (1.0f / 127.0f);
}

// ---------- int8 MFMA GEMM (128x128 tile, 2-phase) — kept for N=2048 gemms ----------
template <int EPI>
__global__ __launch_bounds__(256)
void gemm_i8(const signed char* __restrict__ A, const signed char* __restrict__ Bp,
             int N, int K, const float* __restrict__ wacc, float wcount,
             const float* __restrict__ inv_s, const float* __restrict__ res,
             void* __restrict__ outp) {
  __shared__ signed char As[2][128 * 128];
  int tid = threadIdx.x;
  int idx = blockIdx.x;
  int r8 = idx & 7, rest = idx >> 3;
  int mb = rest & 31;
  int nb = (rest >> 5) * 8 + r8;
  int m0 = mb * 128, n0 = nb * 128;
  int w = tid >> 6, lane = tid & 63;
  int wm = (w >> 1) * 64, wn = (w & 1) * 64;
  int lr = lane & 15, q = lane >> 4;

  v4i acc[4][4] = {};

  int srow = w * 32 + (lane >> 3);
  int scol = (lane & 7) ^ ((lane >> 3) & 7);
  const signed char* ga = A + (long)(m0 + srow) * K + scol * 16;

  int nkb = K >> 7;
  const signed char* gbp[4];
#pragma unroll
  for (int t = 0; t < 4; ++t) {
    int ntile = (n0 >> 4) + (w & 1) * 4 + t;
    gbp[t] = Bp + (long)ntile * (K >> 6) * 1024 + lane * 16;
  }

  v4i bf_cur[2][4], bf_nxt[2][4];
#pragma unroll
  for (int i = 0; i < 4; ++i)
    async_copy16(&As[0][(w * 256 + i * 64) * 16], ga + i * 8 * K);
#pragma unroll
  for (int s = 0; s < 2; ++s)
#pragma unroll
    for (int t = 0; t < 4; ++t) bf_cur[s][t] = *(const v4i*)(gbp[t] + s * 1024);
  __syncthreads();

  int buf = 0;
  for (int kb = 0; kb < nkb; ++kb) {
    if (kb + 1 < nkb) {
#pragma unroll
      for (int i = 0; i < 4; ++i)
        async_copy16(&As[buf ^ 1][(w * 256 + i * 64) * 16], ga + i * 8 * K + (kb + 1) * 128);
#pragma unroll
      for (int s = 0; s < 2; ++s)
#pragma unroll
        for (int t = 0; t < 4; ++t)
          bf_nxt[s][t] = *(const v4i*)(gbp[t] + ((kb + 1) * 2 + s) * 1024);
    }
#pragma unroll
    for (int s = 0; s < 2; ++s) {
      v4i af[4];
#pragma unroll
      for (int i = 0; i < 4; ++i) {
        int row = wm + i * 16 + lr;
        af[i] = *(const v4i*)(&As[buf][(row * 8 + ((s * 4 + q) ^ (lr & 7))) * 16]);
      }
#pragma unroll
      for (int i = 0; i < 4; ++i)
#pragma unroll
        for (int j = 0; j < 4; ++j)
          acc[i][j] = __builtin_amdgcn_mfma_i32_16x16x64_i8(af[i], bf_cur[s][j], acc[i][j], 0, 0, 0);
    }
    __syncthreads();
    if (kb + 1 < nkb) {
#pragma unroll
      for (int s = 0; s < 2; ++s)
#pragma unroll
        for (int t = 0; t < 4; ++t) bf_cur[s][t] = bf_nxt[s][t];
    }
    buf ^= 1;
  }

  float wsv = fmaxf(wacc[0] / wcount, 1e-5f);
#pragma unroll
  for (int i = 0; i < 4; ++i) {
    int rowbase = m0 + wm + i * 16 + (lane >> 4) * 4;
#pragma unroll
    for (int r = 0; r < 4; ++r) {
      int row = rowbase + r;
      float s = wsv * inv_s[row];
#pragma unroll
      for (int j = 0; j < 4; ++j) {
        int col = n0 + wn + j * 16 + (lane & 15);
        long off = (long)row * N + col;
        float v = (float)acc[i][j][r] * s;
        if constexpr (EPI == 0) {
          ((unsigned short*)outp)[off] = f2bf(v);
        } else if constexpr (EPI == 1) {
          ((float*)outp)[off] = v + res[off];
        } else {
          ((unsigned short*)outp)[off] = f2bf(fast_gelu(v));
        }
      }
    }
  }
}

// ========== int8 MFMA GEMM "big": 256x256 tile, BK=128, 8 waves, phase-split (R3-verified) ==========
// All vm ops in the counted-vmcnt window are order-pinned: staging = global_load_lds intrinsics,
// B fragments = asm-volatile global_load_dwordx4. Per-iteration pinned issue order:
// [4 staging][4 B][4 B]. Waits: phase0 vmcnt(4) = prev B drained / staging in flight;
// phase3 tail vmcnt(8) = staging drained / next B in flight. Last iteration peeled.
#define GIB_PHASE(RB, BFC, VMISSUE, WAITSTR, TAIL)                                      \
  {                                                                                     \
    v4i af[4];                                                                          \
    _Pragma("unroll") for (int j = 0; j < 4; ++j) {                                     \
      int m = 2 * p + (j >> 1), kc = j & 1;                                             \
      int row = wm + m * 16 + lr;                                                       \
      af[j] = *(const v4i*)(&As[(RB)][(row * 8 + ((kc * 4 + q) ^ (lr & 7))) * 16]);     \
    }                                                                                   \
    __builtin_amdgcn_sched_barrier(0);                                                  \
    VMISSUE                                                                             \
    __builtin_amdgcn_sched_barrier(0);                                                  \
    __builtin_amdgcn_s_barrier();                                                       \
    asm volatile(WAITSTR ::: "memory");                                                 \
    __builtin_amdgcn_sched_barrier(0);                                                  \
    __builtin_amdgcn_s_setprio(1);                                                      \
    _Pragma("unroll") for (int j = 0; j < 2; ++j)                                       \
      _Pragma("unroll") for (int t = 0; t < 4; ++t)                                     \
        _Pragma("unroll") for (int kc = 0; kc < 2; ++kc)                                \
          acc[2 * p + j][t] = __builtin_amdgcn_mfma_i32_16x16x64_i8(                    \
              af[j * 2 + kc], BFC[kc][t], acc[2 * p + j][t], 0, 0, 0);                  \
    __builtin_amdgcn_s_setprio(0);                                                      \
    __builtin_amdgcn_sched_barrier(0);                                                  \
    TAIL                                                                                \
    __builtin_amdgcn_s_barrier();                                                       \
  }

#define GIB_STAGE(RBD)                                                                  \
  _Pragma("unroll") for (int i = 0; i < 4; ++i)                                         \
    async_copy16(&As[(RBD)][(w * 256 + i * 64) * 16],                                   \
                 ga + (long)i * 8 * K + (kb + 1) * 128);

#define GIB_LOADB(DST, HALF)                                                            \
  _Pragma("unroll") for (int t = 0; t < 4; ++t)                                         \
    asm volatile("global_load_dwordx4 %0, %1, off"                                      \
                 : "=v"(DST[HALF][t])                                                   \
                 : "v"(gbp[t] + (long)((kb + 1) * 2 + (HALF)) * 1024)                   \
                 : "memory");

#define GIB_VMTAIL                                                                      \
  asm volatile("s_waitcnt vmcnt(8)" ::: "memory");                                      \
  __builtin_amdgcn_sched_barrier(0);

#define GIB_ITER_MAIN(RB, BFC, BFN)                                                     \
  {                                                                                     \
    { constexpr int p = 0;                                                              \
      GIB_PHASE(RB, BFC, GIB_STAGE((RB) ^ 1), "s_waitcnt vmcnt(4) lgkmcnt(0)", ) }      \
    { constexpr int p = 1;                                                              \
      GIB_PHASE(RB, BFC, GIB_LOADB(BFN, 0), "s_waitcnt lgkmcnt(0)", ) }                 \
    { constexpr int p = 2;                                                              \
      GIB_PHASE(RB, BFC, GIB_LOADB(BFN, 1), "s_waitcnt lgkmcnt(0)", ) }                 \
    { constexpr int p = 3;                                                              \
      GIB_PHASE(RB, BFC, , "s_waitcnt lgkmcnt(0)", GIB_VMTAIL) }                        \
  }

#define GIB_ITER_LAST(RB, BFC)                                                          \
  {                                                                                     \
    { constexpr int p = 0;                                                              \
      GIB_PHASE(RB, BFC, , "s_waitcnt vmcnt(0) lgkmcnt(0)", ) }                         \
    { constexpr int p = 1;                                                              \
      GIB_PHASE(RB, BFC, , "s_waitcnt lgkmcnt(0)", ) }                                  \
    { constexpr int p = 2;                                                              \
      GIB_PHASE(RB, BFC, , "s_waitcnt lgkmcnt(0)", ) }                                  \
    { constexpr int p = 3;                                                              \
      GIB_PHASE(RB, BFC, , "s_waitcnt lgkmcnt(0)", ) }                                  \
  }

template <int EPI>
__global__ __launch_bounds__(512, 2)
void gemm_i8_big(const signed char* __restrict__ A, const signed char* __restrict__ Bp,
                 int N, int K, const float* __restrict__ wacc, float wcount,
                 const float* __restrict__ inv_s, const float* __restrict__ res,
                 void* __restrict__ outp) {
  __shared__ signed char As[2][256 * 128];
  int tid = threadIdx.x;
  // decode: idx = (n&7) + 8*((n>>3)*16 + m)   [NB % 8 == 0, MB = 16]
  int idx = blockIdx.x;
  int r8 = idx & 7, rest = idx >> 3;
  int mb = rest & 15;
  int nb = (rest >> 4) * 8 + r8;
  int m0 = mb * 256, n0 = nb * 256;
  int w = tid >> 6, lane = tid & 63;
  int wm = (w >> 2) * 128, wn = (w & 3) * 64;
  int lr = lane & 15, q = lane >> 4;

  v4i acc[8][4] = {};

  // A staging: 256 rows x 8 chunks(16B); wave w covers rows [w*32, w*32+32), 4 instrs.
  // LDS chunk u = row*8 + (cg ^ (row&7)); lane-linear dest (w*256 + i*64 + lane)*16.
  int srow = w * 32 + (lane >> 3);
  int scol = (lane & 7) ^ ((lane >> 3) & 7);
  const signed char* ga = A + (long)(m0 + srow) * K + scol * 16;

  int nkt = K >> 7;  // 16 for K=2048 (even, >= 4; loop below relies on this)
  const signed char* gbp[4];
#pragma unroll
  for (int t = 0; t < 4; ++t) {
    int ntile = ((n0 + wn) >> 4) + t;
    gbp[t] = Bp + (long)ntile * (K >> 6) * 1024 + lane * 16;
  }

  v4i bfA[2][4], bfB[2][4];
  // prologue: stage A tile 0 (4 vm), then B frags tile 0 (8 vm, asm-pinned order).
#pragma unroll
  for (int i = 0; i < 4; ++i)
    async_copy16(&As[0][(w * 256 + i * 64) * 16], ga + (long)i * 8 * K);
  __builtin_amdgcn_sched_barrier(0);
#pragma unroll
  for (int s = 0; s < 2; ++s)
#pragma unroll
    for (int t = 0; t < 4; ++t)
      asm volatile("global_load_dwordx4 %0, %1, off"
                   : "=v"(bfA[s][t]) : "v"(gbp[t] + (long)s * 1024) : "memory");
  __builtin_amdgcn_sched_barrier(0);
  asm volatile("s_waitcnt vmcnt(8)" ::: "memory");  // tile-0 staging landed; B in flight
  __builtin_amdgcn_sched_barrier(0);
  __builtin_amdgcn_s_barrier();

  for (int kb2 = 0; kb2 < nkt - 2; kb2 += 2) {
    { int kb = kb2;     GIB_ITER_MAIN(0, bfA, bfB) }
    { int kb = kb2 + 1; GIB_ITER_MAIN(1, bfB, bfA) }
  }
  { int kb = nkt - 2; GIB_ITER_MAIN(0, bfA, bfB) }
  GIB_ITER_LAST(1, bfB)

  float wsv = fmaxf(wacc[0] / wcount, 1e-5f);
#pragma unroll
  for (int m = 0; m < 8; ++m) {
    int rowbase = m0 + wm + m * 16 + q * 4;
#pragma unroll
    for (int r = 0; r < 4; ++r) {
      int row = rowbase + r;
      float s = wsv * inv_s[row];
#pragma unroll
      for (int j = 0; j < 4; ++j) {
        int col = n0 + wn + j * 16 + lr;
        long off = (long)row * N + col;
        float v = (float)acc[m][j][r] * s;
        if constexpr (EPI == 0) {
          ((unsigned short*)outp)[off] = f2bf(v);
        } else if constexpr (EPI == 1) {
          ((float*)outp)[off] = v + res[off];
        } else {
          ((unsigned short*)outp)[off] = f2bf(fast_gelu(v));
        }
      }
    }
  }
}

// ================== MFMA flash attention v2 (verified round 1) + T5 setprio ==================
DEVI int sigma_k(int y) {
  return (y & 35) | (((y >> 3) & 1) << 4) | (((y >> 2) & 1) << 3) | (((y >> 4) & 1) << 2);
}

DEVI void stage_k(const unsigned short* kbase_g, int k0, char* ks, int w, int lane) {
#pragma unroll
  for (int i = 0; i < 2; ++i) {
    int c = i * 512 + w * 64 + lane;
    int key = c >> 4;
    int dch = (c & 15) ^ (key & 15);
    async_copy16(ks + (i * 512 + w * 64) * 16,
                 kbase_g + (long)(k0 + sigma_k(key)) * 6144 + dch * 8);
  }
}

DEVI void load_v(const unsigned short* vbase_g, int k0, int kg, int dg, uint2* lv) {
#pragma unroll
  for (int i = 0; i < 4; ++i)
    lv[i] = *(const uint2*)(vbase_g + (long)(k0 + kg * 4 + i) * 6144 + dg * 4);
}

DEVI void repack_v(const uint2* lv, unsigned short* vt, int kg, int dg) {
#pragma unroll
  for (int jd = 0; jd < 4; ++jd) {
    union { unsigned short s[4]; unsigned long long u; } pk;
#pragma unroll
    for (int i = 0; i < 4; ++i) {
      unsigned word = (jd < 2) ? lv[i].x : lv[i].y;
      pk.s[i] = (unsigned short)((jd & 1) ? (word >> 16) : (word & 0xffffu));
    }
    *(unsigned long long*)(vt + (dg * 4 + jd) * 72 + kg * 4) = pk.u;
  }
}

__global__ __launch_bounds__(512, 4)
void fattn_kernel(const unsigned short* __restrict__ qkv, unsigned short* __restrict__ out) {
  constexpr int VROW = 72;
  __shared__ __align__(16) char Ks[2][16384];
  __shared__ __align__(16) unsigned short Vt[2][128 * VROW];

  int tid = threadIdx.x;
  int w = tid >> 6, lane = tid & 63;
  int l = lane & 15, q = lane >> 4;
  int idx = blockIdx.x;
  int r8 = idx & 7, rest = idx >> 3;
  int qt = rest & 15;
  int bh = (rest >> 4) * 8 + r8;
  int bb = bh >> 4, hh = bh & 15;
  const unsigned short* base = qkv + (long)bb * 2048 * 6144;
  int q0 = qt * 128;

  v8s aq[4];
  {
    const unsigned short* qrow = base + (long)(q0 + w * 16 + l) * 6144 + hh * 128;
#pragma unroll
    for (int kf = 0; kf < 4; ++kf) aq[kf] = *(const v8s*)(qrow + kf * 32 + q * 8);
  }

  v4f oacc[8] = {};
  float mrow = -1e30f, lrow = 0.f;

  const unsigned short* kbase_g = base + 2048 + hh * 128;
  const unsigned short* vbase_g = base + 4096 + hh * 128;
  int kg = tid & 15, dg = tid >> 4;
  constexpr float SC = 0.08838834764831845f;

  stage_k(kbase_g, 0, Ks[0], w, lane);
  uint2 lv[4];
  load_v(vbase_g, 0, kg, dg, lv);
  repack_v(lv, Vt[0], kg, dg);
  __syncthreads();

  for (int kt = 0; kt < 32; ++kt) {
    const char* ksc = Ks[kt & 1];
    const unsigned short* vtc = Vt[kt & 1];
    bool more = kt < 31;
    if (more) {
      stage_k(kbase_g, (kt + 1) * 64, Ks[(kt + 1) & 1], w, lane);
      load_v(vbase_g, (kt + 1) * 64, kg, dg, lv);
    }

    v4f sacc[4] = {};
    __builtin_amdgcn_s_setprio(1);
#pragma unroll
    for (int kf = 0; kf < 4; ++kf) {
#pragma unroll
      for (int t = 0; t < 4; ++t) {
        int ch = (t * 16 + l) * 16 + ((kf * 4 + q) ^ l);
        v8s bk = *(const v8s*)(ksc + ch * 16);
        sacc[t] = __builtin_amdgcn_mfma_f32_16x16x32_bf16(bk, aq[kf], sacc[t], 0, 0, 0);
      }
    }
    __builtin_amdgcn_s_setprio(0);

    float rm = -1e30f;
#pragma unroll
    for (int t = 0; t < 4; ++t)
#pragma unroll
      for (int r = 0; r < 4; ++r) rm = fmaxf(rm, sacc[t][r]);
    rm *= SC;
    rm = fmaxf(rm, __shfl_xor(rm, 16, 64));
    rm = fmaxf(rm, __shfl_xor(rm, 32, 64));
    float mnew = fmaxf(mrow, rm);
    if (__any(mnew - mrow > 8.0f)) {
      float alpha = __expf(mrow - mnew);
      mrow = mnew;
      lrow *= alpha;
#pragma unroll
      for (int r = 0; r < 4; ++r) {
        float ao = __shfl(alpha, q * 4 + r, 64);
#pragma unroll
        for (int t = 0; t < 8; ++t) oacc[t][r] *= ao;
      }
    }
    float rs = 0.f;
#pragma unroll
    for (int t = 0; t < 4; ++t)
#pragma unroll
      for (int r = 0; r < 4; ++r) {
        float pv = __expf(fmaf(sacc[t][r], SC, -mrow));
        sacc[t][r] = pv;
        rs += pv;
      }
    rs += __shfl_xor(rs, 16, 64);
    rs += __shfl_xor(rs, 32, 64);
    lrow += rs;

    union { unsigned u[4]; v8s s; } pa[2];
#pragma unroll
    for (int s2 = 0; s2 < 2; ++s2)
#pragma unroll
      for (int j2 = 0; j2 < 4; ++j2) {
        int tt = s2 * 2 + (j2 >> 1);
        int r0 = (j2 & 1) * 2;
        unsigned wrd;
        asm("v_cvt_pk_bf16_f32 %0, %1, %2"
            : "=v"(wrd) : "v"(sacc[tt][r0]), "v"(sacc[tt][r0 + 1]));
        pa[s2].u[j2] = wrd;
      }

    __builtin_amdgcn_s_setprio(1);
#pragma unroll
    for (int s2 = 0; s2 < 2; ++s2) {
#pragma unroll
      for (int t = 0; t < 8; ++t) {
        v8s bv = *(const v8s*)(vtc + (t * 16 + l) * VROW + s2 * 32 + q * 8);
        oacc[t] = __builtin_amdgcn_mfma_f32_16x16x32_bf16(pa[s2].s, bv, oacc[t], 0, 0, 0);
      }
    }
    __builtin_amdgcn_s_setprio(0);

    if (more) repack_v(lv, Vt[(kt + 1) & 1], kg, dg);
    __syncthreads();
  }

#pragma unroll
  for (int r = 0; r < 4; ++r) {
    float lr = __shfl(lrow, q * 4 + r, 64);
    float inv = 1.0f / lr;
    long grow = (long)bb * 2048 + q0 + w * 16 + q * 4 + r;
    unsigned short* orow = out + grow * 2048 + hh * 128;
#pragma unroll
    for (int t = 0; t < 8; ++t) orow[t * 16 + l] = f2bf(oacc[t][r] * inv);
  }
}

extern "C" void kernel_launch(void* const* d_in, const int* in_sizes, int n_in,
                              void* d_out, int out_size, void* d_ws, size_t ws_size,
                              hipStream_t stream) {
  (void)in_sizes; (void)n_in; (void)out_size; (void)ws_size;
  const float* x      = (const float*)d_in[0];
  const float* w_qkv  = (const float*)d_in[1];
  const float* w_proj = (const float*)d_in[2];
  const float* w_fc1  = (const float*)d_in[3];
  const float* w_fc2  = (const float*)d_in[4];
  const float* g1 = (const float*)d_in[5];
  const float* b1 = (const float*)d_in[6];
  const float* g2 = (const float*)d_in[7];
  const float* b2 = (const float*)d_in[8];

  char* wsb = (char*)d_ws;
  float* acc = (float*)wsb;
  size_t off = 256;
  signed char* q8 = (signed char*)(wsb + off);       off += (size_t)4096 * 8192;
  float* invs = (float*)(wsb + off);                 off += 16384;
  signed char* wq_qkv = (signed char*)(wsb + off);   off += (size_t)6144 * 2048;
  signed char* wq_proj = (signed char*)(wsb + off);  off += (size_t)2048 * 2048;
  signed char* wq_fc1 = (signed char*)(wsb + off);   off += (size_t)8192 * 2048;
  signed char* wq_fc2 = (signed char*)(wsb + off);   off += (size_t)2048 * 8192;
  unsigned short* qkvh = (unsigned short*)(wsb + off); off += (size_t)4096 * 8192 * 2;
  unsigned short* obuf = (unsigned short*)(wsb + off); off += (size_t)4096 * 2048 * 2;
  float* x2 = (float*)(wsb + off);                   off += (size_t)4096 * 2048 * 4;

  hipMemsetAsync(acc, 0, 256, stream);

  absum4_kernel<<<4096, 256, 0, stream>>>(w_qkv, w_proj, w_fc1, w_fc2, acc);
  wquant4_kernel<<<4096, 256, 0, stream>>>(w_qkv, w_proj, w_fc1, w_fc2, acc,
                                           wq_qkv, wq_proj, wq_fc1, wq_fc2);

  ln_quant_kernel<<<4096, 256, 0, stream>>>(x, g1, b1, q8, invs);
  gemm_i8_big<0><<<16 * 24, 512, 0, stream>>>(q8, wq_qkv, 6144, 2048, acc + 0, 12582912.f, invs, nullptr, qkvh);
  fattn_kernel<<<512, 512, 0, stream>>>(qkvh, obuf);
  row_quant_kernel<2048><<<4096, 256, 0, stream>>>(obuf, q8, invs);
  gemm_i8<1><<<16 * 32, 256, 0, stream>>>(q8, wq_proj, 2048, 2048, acc + 1, 4194304.f, invs, x, x2);
  ln_quant_kernel<<<4096, 256, 0, stream>>>(x2, g2, b2, q8, invs);
  gemm_i8_big<2><<<16 * 32, 512, 0, stream>>>(q8, wq_fc1, 8192, 2048, acc + 2, 16777216.f, invs, nullptr, qkvh);
  row_quant_kernel<8192><<<4096, 256, 0, stream>>>(qkvh, q8, invs);
  gemm_i8<1><<<16 * 32, 256, 0, stream>>>(q8, wq_fc2, 2048, 8192, acc + 3, 16777216.f, invs, x2, (float*)d_out);
}